// Round 1
// baseline (199.554 us; speedup 1.0000x reference)
//
#include <hip/hip_runtime.h>
#include <math.h>

#define BS 16
#define QN 900
#define NC 92
#define TN 100
#define NQ (BS * QN)        // 14400
#define NT (BS * TN)        // 1600
#define C_ELEMS ((size_t)NQ * NT)  // 23,040,000
#define NK 15               // ceil(900/64) columns owned per lane

// ---------------------------------------------------------------------------
// sortable-uint float encoding (order-preserving, supports negatives)
// ---------------------------------------------------------------------------
__device__ __forceinline__ unsigned f32_sortable(float f) {
    unsigned u = __float_as_uint(f);
    return (u & 0x80000000u) ? ~u : (u | 0x80000000u);
}
__device__ __forceinline__ float f32_unsortable(unsigned s) {
    return __uint_as_float((s & 0x80000000u) ? (s ^ 0x80000000u) : ~s);
}

// ---------------------------------------------------------------------------
// DPP full-wave f32 min: 6 dependent VALU ops, result valid in lane 63.
// ---------------------------------------------------------------------------
template<int CTRL>
__device__ __forceinline__ float dpp_fmin_step(float x) {
    int xi = __float_as_int(x);
    int yi = __builtin_amdgcn_update_dpp(xi, xi, CTRL, 0xF, 0xF, false);
    return fminf(x, __int_as_float(yi));
}
__device__ __forceinline__ float wave_fmin_to63(float x) {
    x = dpp_fmin_step<0x111>(x);  // row_shr:1
    x = dpp_fmin_step<0x112>(x);  // row_shr:2
    x = dpp_fmin_step<0x114>(x);  // row_shr:4
    x = dpp_fmin_step<0x118>(x);  // row_shr:8
    x = dpp_fmin_step<0x142>(x);  // row_bcast:15
    x = dpp_fmin_step<0x143>(x);  // row_bcast:31
    return x;
}

// uniform slot-select from a per-lane NK-array + readlane broadcast.
__device__ __forceinline__ int read_colreg(const int arr[NK], int c) {
    int v = 0;
    #pragma unroll
    for (int k = 0; k < NK; ++k) if (k == (c >> 6)) v = arr[k];
    return __builtin_amdgcn_readlane(v, c & 63);
}

// ---------------------------------------------------------------------------
// cost of matching pred with target tb (xyxy).
// Pred-derived values hoisted by caller:
//   px2=2*cx, py2=2*cy, pw, ph, corners ax0..ay1, area_a.
// base_cls = 2 - p_cls  (the +2 comes from giou = iou - 1 + uni/area_c).
// cost = 5*cb - p - 2*iou + 2 - 2*uni/area_c
//      = fma(5, cb, base_cls) - 2*(inter*area_c + uni^2) * rcp(uni*area_c)
// One v_rcp_f32 instead of two IEEE divide chains; all fabsf fold into
// VOP3 abs input modifiers; enclosing-box clamps dropped (cx1>=cx0 always).
// ---------------------------------------------------------------------------
__device__ __forceinline__ float cost_entry(
        float px2, float py2, float pw, float ph,
        float ax0, float ay0, float ax1, float ay1,
        float area_a, float base_cls, float4 tb) {
    float tw = tb.z - tb.x;
    float th = tb.w - tb.y;
    float area_b = tw * th;
    // L1 bbox cost: |cx-tcx| = 0.5*|2cx - (x0+x1)|
    float sx = px2 - (tb.x + tb.z);
    float sy = py2 - (tb.y + tb.w);
    float dw = pw - tw;
    float dh = ph - th;
    float cb = fmaf(0.5f, fabsf(sx), fabsf(dw)) + fmaf(0.5f, fabsf(sy), fabsf(dh));
    // intersection
    float ltx = fmaxf(ax0, tb.x), lty = fmaxf(ay0, tb.y);
    float rbx = fminf(ax1, tb.z), rby = fminf(ay1, tb.w);
    float iw = fmaxf(rbx - ltx, 0.0f), ih = fmaxf(rby - lty, 0.0f);
    float inter = iw * ih;
    float uni = (area_a + area_b) - inter;
    // enclosing box (no clamps needed: cx1 >= ax1 >= ax0 >= cx0 etc.)
    float cx0 = fminf(ax0, tb.x), cy0 = fminf(ay0, tb.y);
    float cx1 = fmaxf(ax1, tb.z), cy1 = fmaxf(ay1, tb.w);
    float area_c = (cx1 - cx0) * (cy1 - cy0);
    // inter/uni + uni/area_c  ==  (inter*area_c + uni*uni) / (uni*area_c)
    float num = fmaf(uni, uni, inter * area_c);
    float r   = __builtin_amdgcn_rcpf(uni * area_c);
    return fmaf(-2.0f, num * r, fmaf(5.0f, cb, base_cls));
}

// ---------------------------------------------------------------------------
// Kernel A: fused softmax + full cost matrix C (float4 stores). Wave per query.
// Blocks 0..6 additionally init the rowmin-u64 buffer to all-ones.
// ---------------------------------------------------------------------------
__global__ __launch_bounds__(256) void softmax_cost_kernel(
        const float* __restrict__ logits,
        const float4* __restrict__ pboxes,
        const int4* __restrict__ tids4,
        const float4* __restrict__ tbox,
        float* __restrict__ C,
        unsigned long long* __restrict__ rm) {
    if (blockIdx.x < 7) {
        int idx = blockIdx.x * 256 + threadIdx.x;
        if (idx < NT) rm[idx] = ~0ull;
    }
    __shared__ float shp[4][NC];   // holds (2 - p_cls)
    int wid = threadIdx.x >> 6;
    int lane = threadIdx.x & 63;
    int q = blockIdx.x * 4 + wid;
    const float* row = logits + (size_t)q * NC;
    float x0 = (lane < NC) ? row[lane] : -INFINITY;
    float x1 = (lane + 64 < NC) ? row[lane + 64] : -INFINITY;
    float m = fmaxf(x0, x1);
    for (int off = 32; off; off >>= 1) m = fmaxf(m, __shfl_xor(m, off));
    float e0 = (lane < NC) ? expf(x0 - m) : 0.0f;
    float e1 = (lane + 64 < NC) ? expf(x1 - m) : 0.0f;
    float s = e0 + e1;
    for (int off = 32; off; off >>= 1) s += __shfl_xor(s, off);
    float rs = __builtin_amdgcn_rcpf(s);
    if (lane < NC) shp[wid][lane] = fmaf(-e0, rs, 2.0f);
    if (lane + 64 < NC) shp[wid][lane + 64] = fmaf(-e1, rs, 2.0f);
    __syncthreads();
    // hoist all pred-derived quantities out of the t-loop
    float4 pb = pboxes[q];
    float hx = pb.z * 0.5f, hy = pb.w * 0.5f;
    float ax0 = pb.x - hx, ay0 = pb.y - hy;
    float ax1 = pb.x + hx, ay1 = pb.y + hy;
    float area_a = pb.z * pb.w;
    float px2 = pb.x + pb.x, py2 = pb.y + pb.y;
    float4* crow4 = (float4*)(C + (size_t)q * NT);
    for (int t4 = lane; t4 < NT / 4; t4 += 64) {
        int4 id = tids4[t4];
        int t = t4 * 4;
        float4 r;
        r.x = cost_entry(px2, py2, pb.z, pb.w, ax0, ay0, ax1, ay1, area_a,
                         shp[wid][id.x], tbox[t]);
        r.y = cost_entry(px2, py2, pb.z, pb.w, ax0, ay0, ax1, ay1, area_a,
                         shp[wid][id.y], tbox[t + 1]);
        r.z = cost_entry(px2, py2, pb.z, pb.w, ax0, ay0, ax1, ay1, area_a,
                         shp[wid][id.z], tbox[t + 2]);
        r.w = cost_entry(px2, py2, pb.z, pb.w, ax0, ay0, ax1, ay1, area_a,
                         shp[wid][id.w], tbox[t + 3]);
        crow4[t4] = r;
    }
}

// ---------------------------------------------------------------------------
// Kernel B: transpose C's per-batch diagonal 900x100 block -> cost_t[b][tt][q]
// AND accumulate per-target (min,argmin) via packed-u64 atomicMin.
// ---------------------------------------------------------------------------
__global__ __launch_bounds__(256) void diag_transpose_kernel(
        const float* __restrict__ C, float* __restrict__ cost_t,
        unsigned long long* __restrict__ rm) {
    __shared__ float tile[64][65];
    int b = blockIdx.x;
    int q0 = blockIdx.y * 64;   // 15 q-tiles
    int t0 = blockIdx.z * 64;   // 2 t-tiles
    int tx = threadIdx.x & 63;
    int ty = threadIdx.x >> 6;
    for (int r = ty; r < 64; r += 4) {
        int q = q0 + r, t = t0 + tx;
        if (q < QN && t < TN)
            tile[r][tx] = C[(size_t)(b * QN + q) * NT + b * TN + t];
    }
    __syncthreads();
    for (int r = ty; r < 64; r += 4) {
        int t = t0 + r, q = q0 + tx;
        if (q < QN && t < TN)
            cost_t[(size_t)(b * TN + t) * QN + q] = tile[tx][r];
    }
    if (threadIdx.x < 64) {
        int t = t0 + threadIdx.x;
        if (t < TN) {
            int qmax = min(64, QN - q0);
            float mv = INFINITY; int ma = 0;
            for (int r = 0; r < qmax; ++r) {
                float x = tile[r][threadIdx.x];
                if (x < mv) { mv = x; ma = q0 + r; }  // r asc => q asc: first-min
            }
            unsigned long long key =
                ((unsigned long long)f32_sortable(mv) << 20) | (unsigned)ma;
            atomicMin(&rm[b * TN + t], key);
        }
    }
}

// ---------------------------------------------------------------------------
// Kernel C: exact Hungarian (lazy shortest-augmenting-path), one wave/batch.
// This round: local argmin turned from a 15-deep serial cmp/select chain into
// a depth-4 contiguous pairwise tree (identical first-min tie-breaking:
// left subtree covers strictly smaller column indices and wins ties).
// ---------------------------------------------------------------------------
__global__ __launch_bounds__(64) void lsa_kernel(
        const float* __restrict__ cost_t,
        const unsigned long long* __restrict__ rm,
        float* __restrict__ out) {
    int b = blockIdx.x;
    int lane = threadIdx.x;
    const float* cst = cost_t + (size_t)b * TN * QN;
    __shared__ float u_s[TN];
    __shared__ int p_s[QN];
    __shared__ int unm[TN];
    float v_r[NK], dist_r[NK], rowc[NK];
    int way_r[NK], pcol_r[NK], pj_r[NK];

    // --- init: decode rowmin u64, set duals -------------------------------
    #pragma unroll
    for (int k = 0; k < NK; ++k) { v_r[k] = 0.0f; pcol_r[k] = 0; }
    for (int j = lane; j < QN; j += 64) p_s[j] = 0x7fffffff;
    int arg0 = 0, arg1 = 0;
    float u0 = 0.0f, u1 = 0.0f;
    {
        unsigned long long k0 = rm[b * TN + lane];
        u0 = f32_unsortable((unsigned)(k0 >> 20));
        arg0 = (int)(k0 & 0xFFFFFu);
        u_s[lane] = u0;
        if (lane + 64 < TN) {
            unsigned long long k1 = rm[b * TN + lane + 64];
            u1 = f32_unsortable((unsigned)(k1 >> 20));
            arg1 = (int)(k1 & 0xFFFFFu);
            u_s[lane + 64] = u1;
        }
    }
    // --- greedy: column argmin taken by smallest row index ----------------
    atomicMin(&p_s[arg0], lane + 1);
    if (lane + 64 < TN) atomicMin(&p_s[arg1], lane + 65);
    int nunm = 0;
    {
        bool um0 = (p_s[arg0] != lane + 1);
        unsigned long long m0 = __ballot(um0);
        if (um0) unm[__popcll(m0 & ((1ull << lane) - 1ull))] = lane + 1;
        nunm = __popcll(m0);
        bool um1 = (lane + 64 < TN) && (p_s[arg1] != lane + 65);
        unsigned long long m1 = __ballot(um1);
        if (um1) unm[nunm + __popcll(m1 & ((1ull << lane) - 1ull))] = lane + 65;
        nunm += __popcll(m1);
    }
    #pragma unroll
    for (int k = 0; k < NK; ++k) {
        int c = lane + (k << 6);
        if (c < QN) { int pv = p_s[c]; pcol_r[k] = (pv == 0x7fffffff) ? 0 : pv; }
    }

    // --- shortest augmenting path per unmatched row -----------------------
    for (int ui = 0; ui < nunm; ++ui) {
        int i_cur = unm[ui];
        unsigned used_mask = 0;
        {
            const float* crow = cst + (size_t)(i_cur - 1) * QN;
            float uic = __uint_as_float(__builtin_amdgcn_readlane(
                __float_as_uint((i_cur - 1) < 64 ? u0 : u1), (i_cur - 1) & 63));
            #pragma unroll
            for (int k = 0; k < NK; ++k) {
                int c = lane + (k << 6);
                rowc[k] = (c < QN) ? crow[c] : 0.0f;
                way_r[k] = -1;
                dist_r[k] = (c < QN) ? (rowc[k] - uic - v_r[k]) : INFINITY;
            }
        }
        float dfin; int jfree;
        while (true) {
            // depth-4 pairwise min-tree over masked dist slots.
            // contiguous ranges + strict-less for the right child preserve
            // the original "first (smallest c) wins ties" semantics.
            float dv[16]; int dk[16];
            #pragma unroll
            for (int k = 0; k < NK; ++k) {
                dv[k] = (used_mask & (1u << k)) ? INFINITY : dist_r[k];
                dk[k] = k;
            }
            dv[15] = INFINITY; dk[15] = 15;
            #pragma unroll
            for (int n = 8; n >= 1; n >>= 1) {
                #pragma unroll
                for (int i = 0; i < n; ++i) {
                    bool tk = dv[2 * i + 1] < dv[2 * i];
                    dv[i] = tk ? dv[2 * i + 1] : dv[2 * i];
                    dk[i] = tk ? dk[2 * i + 1] : dk[2 * i];
                }
            }
            float lv = dv[0];
            int li = lane + (dk[0] << 6);
            // global min via DPP, argmin via ballot (lowest lane on exact tie)
            float gm = wave_fmin_to63(lv);
            float dmin = __uint_as_float(__builtin_amdgcn_readlane(__float_as_uint(gm), 63));
            unsigned long long eq = __ballot(lv == dmin);
            int winner = __ffsll(eq) - 1;
            int j1 = __builtin_amdgcn_readlane(li, winner);
            int pj1 = read_colreg(pcol_r, j1);
            if (pj1 == 0) { dfin = dmin; jfree = j1; break; }
            if (lane == (j1 & 63)) {
                int k0 = j1 >> 6;
                used_mask |= 1u << k0;
                pj_r[k0] = pj1;
            }
            // prefetch row pj1 (latency overlaps bookkeeping below)
            {
                const float* crow = cst + (size_t)(pj1 - 1) * QN;
                #pragma unroll
                for (int k = 0; k < NK; ++k) {
                    int c = lane + (k << 6);
                    rowc[k] = (c < QN) ? crow[c] : 0.0f;
                }
            }
            float ui0 = __uint_as_float(__builtin_amdgcn_readlane(
                __float_as_uint((pj1 - 1) < 64 ? u0 : u1), (pj1 - 1) & 63));
            float off = dmin - ui0;   // wave-uniform, hoisted from relax
            #pragma unroll
            for (int k = 0; k < NK; ++k) {
                int c = lane + (k << 6);
                if (c < QN && !(used_mask & (1u << k))) {
                    float nd = (rowc[k] - v_r[k]) + off;
                    if (nd < dist_r[k]) { dist_r[k] = nd; way_r[k] = j1; }
                }
            }
        }
        // dual updates (once per path)
        #pragma unroll
        for (int k = 0; k < NK; ++k) {
            if (used_mask & (1u << k)) {
                float a = dfin - dist_r[k];
                v_r[k] -= a;
                u_s[pj_r[k] - 1] += a;
            }
        }
        if (lane == 0) u_s[i_cur - 1] += dfin;
        u0 = u_s[lane];
        if (lane + 64 < TN) u1 = u_s[lane + 64];
        // augment: walk way chain from the free column
        {
            int jj = jfree;
            while (true) {
                int wj = read_colreg(way_r, jj);
                int pn = (wj < 0) ? i_cur : read_colreg(pcol_r, wj);
                if (lane == (jj & 63)) pcol_r[jj >> 6] = pn;
                if (wj < 0) break;
                jj = wj;
            }
        }
    }

    // --- emit: matched cols ascending == preds ascending ------------------
    float* rows = out + C_ELEMS + (size_t)b * TN;
    float* cols = out + C_ELEMS + (size_t)BS * TN + (size_t)b * TN;
    int base = 0;
    #pragma unroll
    for (int k = 0; k < NK; ++k) {
        int c = lane + (k << 6);
        int pv = (c < QN) ? pcol_r[k] : 0;
        unsigned long long mask = __ballot(pv > 0);
        if (pv > 0) {
            int rank = base + __popcll(mask & ((1ull << lane) - 1ull));
            rows[rank] = (float)c;
            cols[rank] = (float)(pv - 1);
        }
        base += __popcll(mask);
    }
}

extern "C" void kernel_launch(void* const* d_in, const int* in_sizes, int n_in,
                              void* d_out, int out_size, void* d_ws, size_t ws_size,
                              hipStream_t stream) {
    const float* logits = (const float*)d_in[0];        // (16,900,92)
    const float4* pboxes = (const float4*)d_in[1];      // (16,900,4) cxcywh
    const int* tids = (const int*)d_in[2];              // (1600,)
    const float4* tbox = (const float4*)d_in[3];        // (1600,4) xyxy
    float* out = (float*)d_out;

    float* cost_t = (float*)d_ws;                       // BS*TN*QN floats (5.76 MB)
    unsigned long long* rm =
        (unsigned long long*)(cost_t + (size_t)BS * TN * QN);  // NT u64

    softmax_cost_kernel<<<NQ / 4, 256, 0, stream>>>(logits, pboxes, (const int4*)tids, tbox, out, rm);
    diag_transpose_kernel<<<dim3(BS, 15, 2), 256, 0, stream>>>(out, cost_t, rm);
    lsa_kernel<<<BS, 64, 0, stream>>>(cost_t, rm, out);
}

// Round 3
// 176.603 us; speedup vs baseline: 1.1300x; 1.1300x over previous
//
#include <hip/hip_runtime.h>
#include <math.h>

#define BS 16
#define QN 900
#define NC 92
#define TN 100
#define NQ (BS * QN)        // 14400
#define NT (BS * TN)        // 1600
#define C_ELEMS ((size_t)NQ * NT)  // 23,040,000
#define NK 15               // scalar ownership (emit pass)
#define F4N 225             // float4 chunks per 900-col row
#define NS 16               // 4 float4-slots x 4 components per lane
#define ARR_CAP 300         // max ARR pops (tie-cycle guard)
#define UNM_CAP 416         // queue capacity: nunm(<=100) + kicks(<=ARR_CAP)

// ---------------------------------------------------------------------------
// sortable-uint float encoding (order-preserving, supports negatives)
// ---------------------------------------------------------------------------
__device__ __forceinline__ unsigned f32_sortable(float f) {
    unsigned u = __float_as_uint(f);
    return (u & 0x80000000u) ? ~u : (u | 0x80000000u);
}
__device__ __forceinline__ float f32_unsortable(unsigned s) {
    return __uint_as_float((s & 0x80000000u) ? (s ^ 0x80000000u) : ~s);
}

// ---------------------------------------------------------------------------
// DPP full-wave f32 min: 6 dependent VALU ops, result valid in lane 63.
// ---------------------------------------------------------------------------
template<int CTRL>
__device__ __forceinline__ float dpp_fmin_step(float x) {
    int xi = __float_as_int(x);
    int yi = __builtin_amdgcn_update_dpp(xi, xi, CTRL, 0xF, 0xF, false);
    return fminf(x, __int_as_float(yi));
}
__device__ __forceinline__ float wave_fmin_to63(float x) {
    x = dpp_fmin_step<0x111>(x);  // row_shr:1
    x = dpp_fmin_step<0x112>(x);  // row_shr:2
    x = dpp_fmin_step<0x114>(x);  // row_shr:4
    x = dpp_fmin_step<0x118>(x);  // row_shr:8
    x = dpp_fmin_step<0x142>(x);  // row_bcast:15
    x = dpp_fmin_step<0x143>(x);  // row_bcast:31
    return x;
}
__device__ __forceinline__ float readlane63_f(float x) {
    return __uint_as_float(__builtin_amdgcn_readlane(__float_as_uint(x), 63));
}

// column c -> (slot, owner lane) under the float4 ownership map:
// c = 4*(lane + 64k) + j,  slot s = 4k + j
__device__ __forceinline__ int slot_of(int c) { return ((c >> 8) << 2) | (c & 3); }
__device__ __forceinline__ int owner_of(int c) { return (c >> 2) & 63; }

__device__ __forceinline__ int read_colreg16(const int arr[NS], int c) {
    int s = slot_of(c);
    int v = 0;
    #pragma unroll
    for (int k = 0; k < NS; ++k) if (k == s) v = arr[k];
    return __builtin_amdgcn_readlane(v, owner_of(c));
}

// uniform row-dual read from register mirrors (r is wave-uniform)
__device__ __forceinline__ float readrow_u(float u0, float u1, int r) {
    return __uint_as_float(__builtin_amdgcn_readlane(
        __float_as_uint(r < 64 ? u0 : u1), r & 63));
}

// issue one cost row (900 floats) as 4 dwordx4 loads per lane
__device__ __forceinline__ void issue_row(const float4* cst4, int irow, int lane,
        float4& r0, float4& r1, float4& r2, float4& r3) {
    const float4* cr = cst4 + (size_t)(irow - 1) * F4N;
    r0 = cr[lane];
    r1 = cr[lane + 64];
    r2 = cr[lane + 128];
    if (lane < 33) r3 = cr[lane + 192];
}

// ---------------------------------------------------------------------------
// cost of matching pred with target tb (xyxy).  (unchanged, passing since r1)
// ---------------------------------------------------------------------------
__device__ __forceinline__ float cost_entry(
        float px2, float py2, float pw, float ph,
        float ax0, float ay0, float ax1, float ay1,
        float area_a, float base_cls, float4 tb) {
    float tw = tb.z - tb.x;
    float th = tb.w - tb.y;
    float area_b = tw * th;
    float sx = px2 - (tb.x + tb.z);
    float sy = py2 - (tb.y + tb.w);
    float dw = pw - tw;
    float dh = ph - th;
    float cb = fmaf(0.5f, fabsf(sx), fabsf(dw)) + fmaf(0.5f, fabsf(sy), fabsf(dh));
    float ltx = fmaxf(ax0, tb.x), lty = fmaxf(ay0, tb.y);
    float rbx = fminf(ax1, tb.z), rby = fminf(ay1, tb.w);
    float iw = fmaxf(rbx - ltx, 0.0f), ih = fmaxf(rby - lty, 0.0f);
    float inter = iw * ih;
    float uni = (area_a + area_b) - inter;
    float cx0 = fminf(ax0, tb.x), cy0 = fminf(ay0, tb.y);
    float cx1 = fmaxf(ax1, tb.z), cy1 = fmaxf(ay1, tb.w);
    float area_c = (cx1 - cx0) * (cy1 - cy0);
    float num = fmaf(uni, uni, inter * area_c);
    float r   = __builtin_amdgcn_rcpf(uni * area_c);
    return fmaf(-2.0f, num * r, fmaf(5.0f, cb, base_cls));
}

// ---------------------------------------------------------------------------
// Kernel A: fused softmax + full cost matrix C.  (unchanged, passing since r1)
// ---------------------------------------------------------------------------
__global__ __launch_bounds__(256) void softmax_cost_kernel(
        const float* __restrict__ logits,
        const float4* __restrict__ pboxes,
        const int4* __restrict__ tids4,
        const float4* __restrict__ tbox,
        float* __restrict__ C,
        unsigned long long* __restrict__ rm) {
    if (blockIdx.x < 7) {
        int idx = blockIdx.x * 256 + threadIdx.x;
        if (idx < NT) rm[idx] = ~0ull;
    }
    __shared__ float shp[4][NC];   // holds (2 - p_cls)
    int wid = threadIdx.x >> 6;
    int lane = threadIdx.x & 63;
    int q = blockIdx.x * 4 + wid;
    const float* row = logits + (size_t)q * NC;
    float x0 = (lane < NC) ? row[lane] : -INFINITY;
    float x1 = (lane + 64 < NC) ? row[lane + 64] : -INFINITY;
    float m = fmaxf(x0, x1);
    for (int off = 32; off; off >>= 1) m = fmaxf(m, __shfl_xor(m, off));
    float e0 = (lane < NC) ? expf(x0 - m) : 0.0f;
    float e1 = (lane + 64 < NC) ? expf(x1 - m) : 0.0f;
    float s = e0 + e1;
    for (int off = 32; off; off >>= 1) s += __shfl_xor(s, off);
    float rs = __builtin_amdgcn_rcpf(s);
    if (lane < NC) shp[wid][lane] = fmaf(-e0, rs, 2.0f);
    if (lane + 64 < NC) shp[wid][lane + 64] = fmaf(-e1, rs, 2.0f);
    __syncthreads();
    float4 pb = pboxes[q];
    float hx = pb.z * 0.5f, hy = pb.w * 0.5f;
    float ax0 = pb.x - hx, ay0 = pb.y - hy;
    float ax1 = pb.x + hx, ay1 = pb.y + hy;
    float area_a = pb.z * pb.w;
    float px2 = pb.x + pb.x, py2 = pb.y + pb.y;
    float4* crow4 = (float4*)(C + (size_t)q * NT);
    for (int t4 = lane; t4 < NT / 4; t4 += 64) {
        int4 id = tids4[t4];
        int t = t4 * 4;
        float4 r;
        r.x = cost_entry(px2, py2, pb.z, pb.w, ax0, ay0, ax1, ay1, area_a,
                         shp[wid][id.x], tbox[t]);
        r.y = cost_entry(px2, py2, pb.z, pb.w, ax0, ay0, ax1, ay1, area_a,
                         shp[wid][id.y], tbox[t + 1]);
        r.z = cost_entry(px2, py2, pb.z, pb.w, ax0, ay0, ax1, ay1, area_a,
                         shp[wid][id.z], tbox[t + 2]);
        r.w = cost_entry(px2, py2, pb.z, pb.w, ax0, ay0, ax1, ay1, area_a,
                         shp[wid][id.w], tbox[t + 3]);
        crow4[t4] = r;
    }
}

// ---------------------------------------------------------------------------
// Kernel B: transpose + per-target (min,argmin).  (unchanged, passing)
// ---------------------------------------------------------------------------
__global__ __launch_bounds__(256) void diag_transpose_kernel(
        const float* __restrict__ C, float* __restrict__ cost_t,
        unsigned long long* __restrict__ rm) {
    __shared__ float tile[64][65];
    int b = blockIdx.x;
    int q0 = blockIdx.y * 64;
    int t0 = blockIdx.z * 64;
    int tx = threadIdx.x & 63;
    int ty = threadIdx.x >> 6;
    for (int r = ty; r < 64; r += 4) {
        int q = q0 + r, t = t0 + tx;
        if (q < QN && t < TN)
            tile[r][tx] = C[(size_t)(b * QN + q) * NT + b * TN + t];
    }
    __syncthreads();
    for (int r = ty; r < 64; r += 4) {
        int t = t0 + r, q = q0 + tx;
        if (q < QN && t < TN)
            cost_t[(size_t)(b * TN + t) * QN + q] = tile[tx][r];
    }
    if (threadIdx.x < 64) {
        int t = t0 + threadIdx.x;
        if (t < TN) {
            int qmax = min(64, QN - q0);
            float mv = INFINITY; int ma = 0;
            for (int r = 0; r < qmax; ++r) {
                float x = tile[r][threadIdx.x];
                if (x < mv) { mv = x; ma = q0 + r; }
            }
            unsigned long long key =
                ((unsigned long long)f32_sortable(mv) << 20) | (unsigned)ma;
            atomicMin(&rm[b * TN + t], key);
        }
    }
}

// ---------------------------------------------------------------------------
// Kernel C: exact Hungarian, one wave/batch.
// Round-3: r2's v-init REMOVED (proven wrong: v>0 on free columns breaks the
// extremality invariant "v<=0 matched / v=0 free" -- counterexample in log).
// Replaced with LAPJV augmenting-row-reduction (ARR): for unmatched row i,
// d=c[i]-v, u[i]=d2, v[j1]-=(d2-d1) (<=0, matched col only -> invariant OK),
// take j1, kick+requeue owner; exact-tie on occupied column -> Dijkstra list.
// Kept from r2 (plumbing verified): float4 ownership remap, float4 row loads,
// next-row prefetch.  Dropped pj_r (pcol_r is unchanged until augment).
// ---------------------------------------------------------------------------
__global__ __launch_bounds__(64, 1) void lsa_kernel(
        const float* __restrict__ cost_t,
        const unsigned long long* __restrict__ rm,
        float* __restrict__ out) {
    int b = blockIdx.x;
    int lane = threadIdx.x;
    const float4* cst4 = (const float4*)(cost_t + (size_t)b * TN * QN);
    __shared__ float u_s[TN];
    __shared__ int p_s[QN];
    __shared__ int unm[UNM_CAP];
    __shared__ int dij[128];

    float v_r[NS], dist_r[NS];
    int way_r[NS], pcol_r[NS];
    float4 pre0, pre1, pre2, pre3 = make_float4(0.f, 0.f, 0.f, 0.f);
    float4 rc0, rc1, rc2, rc3 = make_float4(0.f, 0.f, 0.f, 0.f);
    const bool v3 = (lane < 33);   // slot 12-15 validity: lane+192 < 225

    // --- init: decode rowmin u64, set duals -------------------------------
    #pragma unroll
    for (int s = 0; s < NS; ++s) v_r[s] = 0.0f;
    for (int j = lane; j < QN; j += 64) p_s[j] = 0x7fffffff;
    int arg0 = 0, arg1 = 0;
    float u0 = 0.0f, u1 = 0.0f;
    {
        unsigned long long kk = rm[b * TN + lane];
        u0 = f32_unsortable((unsigned)(kk >> 20));
        arg0 = (int)(kk & 0xFFFFFu);
        u_s[lane] = u0;
        if (lane + 64 < TN) {
            unsigned long long k1 = rm[b * TN + lane + 64];
            u1 = f32_unsortable((unsigned)(k1 >> 20));
            arg1 = (int)(k1 & 0xFFFFFu);
            u_s[lane + 64] = u1;
        }
    }
    // --- greedy: column argmin taken by smallest row index ----------------
    atomicMin(&p_s[arg0], lane + 1);
    if (lane + 64 < TN) atomicMin(&p_s[arg1], lane + 65);
    int nunm = 0;
    {
        bool um0 = (p_s[arg0] != lane + 1);
        unsigned long long m0 = __ballot(um0);
        if (um0) unm[__popcll(m0 & ((1ull << lane) - 1ull))] = lane + 1;
        nunm = __popcll(m0);
        bool um1 = (lane + 64 < TN) && (p_s[arg1] != lane + 65);
        unsigned long long m1 = __ballot(um1);
        if (um1) unm[nunm + __popcll(m1 & ((1ull << lane) - 1ull))] = lane + 65;
        nunm += __popcll(m1);
    }
    #pragma unroll
    for (int s = 0; s < NS; ++s) {
        int f = lane + ((s >> 2) << 6);
        int c = (f << 2) | (s & 3);
        pcol_r[s] = 0;
        if (f < F4N) { int pv = p_s[c]; pcol_r[s] = (pv == 0x7fffffff) ? 0 : pv; }
    }

    // --- ARR phase: resolve greedy collisions cheaply ---------------------
    int qhead = 0, qtail = nunm, dij_n = 0, pops = 0;
    if (qhead < qtail) issue_row(cst4, unm[0], lane, pre0, pre1, pre2, pre3);
    while (qhead < qtail) {
        int i_cur = unm[qhead++];
        ++pops;
        if (pops > ARR_CAP) {           // tie-cycle guard: drain rest to Dijkstra
            if (lane == 0) dij[dij_n] = i_cur;
            dij_n++;
            continue;                   // pre never consumed after cap
        }
        // d = row - v  (pre holds row i_cur)
        float dd[NS];
        dd[0]  = pre0.x - v_r[0];  dd[1]  = pre0.y - v_r[1];
        dd[2]  = pre0.z - v_r[2];  dd[3]  = pre0.w - v_r[3];
        dd[4]  = pre1.x - v_r[4];  dd[5]  = pre1.y - v_r[5];
        dd[6]  = pre1.z - v_r[6];  dd[7]  = pre1.w - v_r[7];
        dd[8]  = pre2.x - v_r[8];  dd[9]  = pre2.y - v_r[9];
        dd[10] = pre2.z - v_r[10]; dd[11] = pre2.w - v_r[11];
        if (v3) {
            dd[12] = pre3.x - v_r[12]; dd[13] = pre3.y - v_r[13];
            dd[14] = pre3.z - v_r[14]; dd[15] = pre3.w - v_r[15];
        } else {
            dd[12] = INFINITY; dd[13] = INFINITY;
            dd[14] = INFINITY; dd[15] = INFINITY;
        }
        // prefetch next queued row (latency hides under the reduce below)
        bool pf = false;
        if (qhead < qtail) { issue_row(cst4, unm[qhead], lane, pre0, pre1, pre2, pre3); pf = true; }
        // local min + second-min over 16 slots
        float l1 = INFINITY, l2 = INFINITY; int ls = 0;
        #pragma unroll
        for (int s = 0; s < NS; ++s) {
            float d = dd[s];
            bool lt = d < l1;
            l2 = lt ? l1 : fminf(l2, d);
            ls = lt ? s : ls;
            l1 = lt ? d : l1;
        }
        // wave min (d1, j1) and second-min d2
        float d1 = readlane63_f(wave_fmin_to63(l1));
        unsigned long long eqm = __ballot(l1 == d1);
        int wl = __ffsll(eqm) - 1;
        float cand2 = (lane == wl) ? l2 : l1;
        float d2 = readlane63_f(wave_fmin_to63(cand2));
        int myj = (lane << 2) + ((ls >> 2) << 8) + (ls & 3);
        int j1 = __builtin_amdgcn_readlane(myj, wl);
        int i0 = read_colreg16(pcol_r, j1);
        bool take = (d1 < d2) || (i0 == 0);
        if (take) {
            int s1 = slot_of(j1), ow = owner_of(j1);
            float dv_ = d2 - d1;
            #pragma unroll
            for (int s = 0; s < NS; ++s)
                if (s == s1 && lane == ow) { v_r[s] -= dv_; pcol_r[s] = i_cur; }
            if (lane == 0) {
                u_s[i_cur - 1] = d2;
                if (i0 != 0) unm[qtail] = i0;
            }
            if (i0 != 0) qtail++;
        } else {
            if (lane == 0) { u_s[i_cur - 1] = d2; dij[dij_n] = i_cur; }
            dij_n++;
        }
        if (!pf && qhead < qtail)   // queue was empty but a kick appended
            issue_row(cst4, unm[qhead], lane, pre0, pre1, pre2, pre3);
    }
    // refresh register u mirrors after ARR writes
    u0 = u_s[lane];
    if (lane + 64 < TN) u1 = u_s[lane + 64];

    // --- shortest augmenting path for rows ARR couldn't place -------------
    if (dij_n > 0) issue_row(cst4, dij[0], lane, pre0, pre1, pre2, pre3);

    for (int ui = 0; ui < dij_n; ++ui) {
        int i_cur = dij[ui];
        unsigned used_mask = 0;
        float uic = readrow_u(u0, u1, i_cur - 1);
        #pragma unroll
        for (int s = 0; s < NS; ++s) way_r[s] = -1;
        dist_r[0]  = (pre0.x - uic) - v_r[0];
        dist_r[1]  = (pre0.y - uic) - v_r[1];
        dist_r[2]  = (pre0.z - uic) - v_r[2];
        dist_r[3]  = (pre0.w - uic) - v_r[3];
        dist_r[4]  = (pre1.x - uic) - v_r[4];
        dist_r[5]  = (pre1.y - uic) - v_r[5];
        dist_r[6]  = (pre1.z - uic) - v_r[6];
        dist_r[7]  = (pre1.w - uic) - v_r[7];
        dist_r[8]  = (pre2.x - uic) - v_r[8];
        dist_r[9]  = (pre2.y - uic) - v_r[9];
        dist_r[10] = (pre2.z - uic) - v_r[10];
        dist_r[11] = (pre2.w - uic) - v_r[11];
        if (v3) {
            dist_r[12] = (pre3.x - uic) - v_r[12];
            dist_r[13] = (pre3.y - uic) - v_r[13];
            dist_r[14] = (pre3.z - uic) - v_r[14];
            dist_r[15] = (pre3.w - uic) - v_r[15];
        } else {
            dist_r[12] = INFINITY; dist_r[13] = INFINITY;
            dist_r[14] = INFINITY; dist_r[15] = INFINITY;
        }
        if (ui + 1 < dij_n) issue_row(cst4, dij[ui + 1], lane, pre0, pre1, pre2, pre3);

        float dfin; int jfree;
        while (true) {
            // depth-4 pairwise min-tree over masked dist slots
            float dv[NS]; int dk[NS];
            #pragma unroll
            for (int s = 0; s < NS; ++s) {
                dv[s] = (used_mask & (1u << s)) ? INFINITY : dist_r[s];
                dk[s] = s;
            }
            #pragma unroll
            for (int n = 8; n >= 1; n >>= 1) {
                #pragma unroll
                for (int i = 0; i < n; ++i) {
                    bool tk = dv[2 * i + 1] < dv[2 * i];
                    dv[i] = tk ? dv[2 * i + 1] : dv[2 * i];
                    dk[i] = tk ? dk[2 * i + 1] : dk[2 * i];
                }
            }
            float lv = dv[0];
            int s0 = dk[0];
            int li = (lane << 2) + ((s0 >> 2) << 8) + (s0 & 3);
            float dmin = readlane63_f(wave_fmin_to63(lv));
            unsigned long long eq = __ballot(lv == dmin);
            int winner = __ffsll(eq) - 1;
            int j1 = __builtin_amdgcn_readlane(li, winner);
            int pj1 = read_colreg16(pcol_r, j1);
            if (pj1 == 0) { dfin = dmin; jfree = j1; break; }
            {
                int s1 = slot_of(j1), ow1 = owner_of(j1);
                if (lane == ow1) used_mask |= (1u << s1);
            }
            // row pj1 load issued first; readlane/bookkeeping overlap latency
            issue_row(cst4, pj1, lane, rc0, rc1, rc2, rc3);
            float ui0 = readrow_u(u0, u1, pj1 - 1);
            float off = dmin - ui0;   // wave-uniform
            #define RELAX(S, V) \
                if (!(used_mask & (1u << (S)))) { \
                    float nd = ((V) - v_r[S]) + off; \
                    if (nd < dist_r[S]) { dist_r[S] = nd; way_r[S] = j1; } }
            RELAX(0,  rc0.x) RELAX(1,  rc0.y) RELAX(2,  rc0.z) RELAX(3,  rc0.w)
            RELAX(4,  rc1.x) RELAX(5,  rc1.y) RELAX(6,  rc1.z) RELAX(7,  rc1.w)
            RELAX(8,  rc2.x) RELAX(9,  rc2.y) RELAX(10, rc2.z) RELAX(11, rc2.w)
            if (v3) {
                RELAX(12, rc3.x) RELAX(13, rc3.y) RELAX(14, rc3.z) RELAX(15, rc3.w)
            }
            #undef RELAX
        }
        // dual updates (once per path); pcol_r unchanged until augment below
        #pragma unroll
        for (int s = 0; s < NS; ++s) {
            if (used_mask & (1u << s)) {
                float a = dfin - dist_r[s];
                v_r[s] -= a;
                u_s[pcol_r[s] - 1] += a;   // distinct rows => distinct addresses
            }
        }
        if (lane == 0) u_s[i_cur - 1] += dfin;
        u0 = u_s[lane];
        if (lane + 64 < TN) u1 = u_s[lane + 64];
        // augment: walk way chain from the free column
        {
            int jj = jfree;
            while (true) {
                int wj = read_colreg16(way_r, jj);
                int pn = (wj < 0) ? i_cur : read_colreg16(pcol_r, wj);
                int sj = slot_of(jj), ow = owner_of(jj);
                #pragma unroll
                for (int s = 0; s < NS; ++s)
                    if (s == sj && lane == ow) pcol_r[s] = pn;
                if (wj < 0) break;
                jj = wj;
            }
        }
    }

    // --- emit: write pcol back to LDS by column for ascending-order pass --
    #pragma unroll
    for (int s = 0; s < NS; ++s) {
        int f = lane + ((s >> 2) << 6);
        int c = (f << 2) | (s & 3);
        if (f < F4N) p_s[c] = pcol_r[s];
    }
    float* rows = out + C_ELEMS + (size_t)b * TN;
    float* cols = out + C_ELEMS + (size_t)BS * TN + (size_t)b * TN;
    int base = 0;
    #pragma unroll
    for (int k = 0; k < NK; ++k) {
        int c = lane + (k << 6);
        int pv = (c < QN) ? p_s[c] : 0;
        unsigned long long mask = __ballot(pv > 0);
        if (pv > 0) {
            int rank = base + __popcll(mask & ((1ull << lane) - 1ull));
            rows[rank] = (float)c;
            cols[rank] = (float)(pv - 1);
        }
        base += __popcll(mask);
    }
}

extern "C" void kernel_launch(void* const* d_in, const int* in_sizes, int n_in,
                              void* d_out, int out_size, void* d_ws, size_t ws_size,
                              hipStream_t stream) {
    const float* logits = (const float*)d_in[0];        // (16,900,92)
    const float4* pboxes = (const float4*)d_in[1];      // (16,900,4) cxcywh
    const int* tids = (const int*)d_in[2];              // (1600,)
    const float4* tbox = (const float4*)d_in[3];        // (1600,4) xyxy
    float* out = (float*)d_out;

    float* cost_t = (float*)d_ws;                       // BS*TN*QN floats (5.76 MB)
    unsigned long long* rm =
        (unsigned long long*)(cost_t + (size_t)BS * TN * QN);  // NT u64

    softmax_cost_kernel<<<NQ / 4, 256, 0, stream>>>(logits, pboxes, (const int4*)tids, tbox, out, rm);
    diag_transpose_kernel<<<dim3(BS, 15, 2), 256, 0, stream>>>(out, cost_t, rm);
    lsa_kernel<<<BS, 64, 0, stream>>>(cost_t, rm, out);
}